// Round 12
// baseline (645.858 us; speedup 1.0000x reference)
//
#include <hip/hip_runtime.h>
#include <hip/hip_bf16.h>

#define HH 96
#define WW 96
#define CC 21
#define NN (HH*WW)          // 9216
#define NELEM (NN*CC)       // 193536
#define RS 20
#define NPAR (2*CC + CC*CC)
#define L2E 1.4426950408889634f
#define NMC 48              // 12x16 m-chunks: 8 y * 6 x
#define NBB (36*NMC)
#define NBLUR (CC*8)        // 168 blur items
#define SROWS 12
#define TRUNC2 900          // 30^2 (validated R10: absmax 0.015625 unchanged)
#define BLURKEY 0x10000

typedef short bf16x8 __attribute__((ext_vector_type(8)));
typedef float f32x16 __attribute__((ext_vector_type(16)));

__device__ __forceinline__ float fexp2(float x) { return __builtin_amdgcn_exp2f(x); }
__device__ __forceinline__ float fexp(float x)  { return __builtin_amdgcn_exp2f(x * L2E); }

__device__ __forceinline__ short f2b(float f) {
    __hip_bfloat16 h = __float2bfloat16(f);
    short s; __builtin_memcpy(&s, &h, 2); return s;
}

// ---- compile-time work table + per-tile expected completion counts.
struct Tab { int n; int k[NBB + NBLUR]; int expct[36]; };
constexpr Tab build_tab() {
    Tab t{};
    int key[NBB + NBLUR] = {};
    int cst[NBB + NBLUR] = {};
    int m = 0;
    for (int nt = 0; nt < 36; nt++) t.expct[nt] = 42;   // 2 strips x 21 ch
    for (int nt = 0; nt < 36; nt++)
        for (int mc = 0; mc < NMC; mc++) {
            const int ny0 = (nt / 6) * 16, nx0 = (nt % 6) * 16;
            const int my0 = (mc & 7) * 12, mx0 = (mc >> 3) * 16;
            const int dx = (mx0 > nx0 + 15) ? mx0 - (nx0 + 15)
                         : ((nx0 > mx0 + 15) ? nx0 - (mx0 + 15) : 0);
            const int lim = TRUNC2 - dx * dx;
            if (lim < 0) continue;
            int T = 0;
            while ((T + 1) * (T + 1) <= lim) T++;
            int cost = 0;
            for (int wv = 0; wv < 4; wv++) {
                const int by0 = ny0 + 4 * wv;
                int lo = by0 - T - my0;     if (lo < 0)  lo = 0;
                int hi = by0 + 3 + T - my0; if (hi > 11) hi = 11;
                if (lo <= hi) cost += hi - lo + 1;
            }
            if (cost == 0) continue;
            key[m] = (nt << 6) | mc; cst[m] = cost; m++;
            t.expct[nt]++;
        }
    for (int b = 0; b < NBLUR; b++) { key[m] = BLURKEY + b; cst[m] = 20; m++; }
    for (int c = 48; c >= 1; c--)                 // stable counting sort, desc
        for (int i = 0; i < m; i++)
            if (cst[i] == c) t.k[t.n++] = key[i];
    return t;
}
constexpr Tab TT = build_tab();
__device__ __constant__ Tab c_TT = TT;

// ---- dtype sniff: bf16 data never contains exp=0xFF bit patterns.
__global__ void k_sniff(const unsigned short* __restrict__ u16, int* __restrict__ flag32) {
    __shared__ int sfound;
    if (threadIdx.x == 0) sfound = 0;
    __syncthreads();
    const int base = blockIdx.x * (NELEM/32);
    int found = 0;
    for (int i = base + threadIdx.x; i < base + NELEM/32; i += 256) {
        unsigned v = u16[i];
        if ((v & 0x7F80u) == 0x7F80u) found = 1;
    }
    if (found) sfound = 1;
    __syncthreads();
    if (threadIdx.x == 0) flag32[blockIdx.x] = sfound;
}

__device__ __forceinline__ int rdflag(const int* __restrict__ flag32) {
    int f = 0;
    #pragma unroll
    for (int i = 0; i < 32; i++) f |= flag32[i];
    return f;
}

// Fused prep: featx, params, softmax(u)->pT0, zero bil + tile counters.
__global__ __launch_bounds__(256) void k_prep(
    const void* __restrict__ u, const void* __restrict__ img,
    const void* __restrict__ wS, const void* __restrict__ wB,
    const void* __restrict__ compat, const int* __restrict__ flag32,
    float* __restrict__ uf, float* __restrict__ featx, float* __restrict__ par,
    float* __restrict__ bil, __hip_bfloat16* __restrict__ pT, int* __restrict__ cnt)
{
    const int f = rdflag(flag32);
    const int tid = threadIdx.x;
    const int n = blockIdx.x * 256 + tid;

    if (blockIdx.x == 0) {
        if (tid < 36) cnt[tid] = 0;
        for (int i = tid; i < NPAR; i += 256) {
            const void* src; int j;
            if (i < CC)        { src = wS;     j = i; }
            else if (i < 2*CC) { src = wB;     j = i - CC; }
            else               { src = compat; j = i - 2*CC; }
            par[i] = f ? ((const float*)src)[j]
                       : __bfloat162float(((const __hip_bfloat16*)src)[j]);
        }
    }

    {
        float c0, c1, c2;
        if (f) { const float* p = (const float*)img;
                 c0 = p[3*n]; c1 = p[3*n+1]; c2 = p[3*n+2]; }
        else   { const __hip_bfloat16* p = (const __hip_bfloat16*)img;
                 c0 = __bfloat162float(p[3*n]); c1 = __bfloat162float(p[3*n+1]);
                 c2 = __bfloat162float(p[3*n+2]); }
        float ym = (float)(n / WW), xm = (float)(n % WW);
        const float sc = 0.15014029f;   // sqrt(2*L2E/128)
        const float cf = 9.6089787f;    // sqrt(64*L2E)
        featx[8*n + 0] = -L2E * (fmaf(ym, ym, xm*xm) * 0.0078125f
                                 + 32.f * (c0*c0 + c1*c1 + c2*c2));
        featx[8*n + 1] = sc * ym;
        featx[8*n + 2] = sc * xm;
        featx[8*n + 3] = cf * c0;
        featx[8*n + 4] = cf * c1;
        featx[8*n + 5] = cf * c2;
        featx[8*n + 6] = 0.f;
        featx[8*n + 7] = 0.f;
    }

    float v[CC];
    float mx = -1e30f;
    #pragma unroll
    for (int c = 0; c < CC; c++) {
        float uv = f ? ((const float*)u)[n*CC + c]
                     : __bfloat162float(((const __hip_bfloat16*)u)[n*CC + c]);
        uf[n*CC + c] = uv;
        v[c] = uv;
        mx = fmaxf(mx, uv);
    }
    float s = 0.f;
    #pragma unroll
    for (int c = 0; c < CC; c++) { v[c] = fexp(v[c] - mx); s += v[c]; }
    float inv = 1.f / s;
    #pragma unroll
    for (int c = 0; c < CC; c++) {
        pT[(size_t)c*NN + n] = __float2bfloat16(v[c] * inv);
        bil[(size_t)c*NN + n] = 0.f;
    }
}

// Fused work+update kernel. Work items (bilateral MFMA / blur) credit per-tile
// completion counters; the block that completes a tile performs that tile's
// update (message combine + compat + q + softmax) inline, writing pTnxt.
// pT is double-buffered so same-launch readers of pTcur never race.
__global__ __launch_bounds__(256) void k_work(
    const __hip_bfloat16* __restrict__ pTcur,  // [32][NN] iteration input
    __hip_bfloat16* __restrict__ pTnxt,        // [32][NN] iteration output
    const float* __restrict__ featx,           // [NN][8]
    float* __restrict__ bil,                   // [CC][NN] atomic accum
    float* __restrict__ s2T,                   // [CC][NN] spatial out
    const float* __restrict__ uf, const float* __restrict__ par,
    const int* __restrict__ flag32, int* __restrict__ cnt,
    void* __restrict__ out, int last)
{
    __shared__ float smem[6176];
    __shared__ int fin[13];                    // [0]=count, [1..12]=tile ids
    const int tid = threadIdx.x;
    const int item = c_TT.k[blockIdx.x];
    if (tid == 0) fin[0] = 0;

    if (item < BLURKEY) {
        // ---------------- bilateral: bil[c][n] += sum_m pT[c][m] * K(n,m)
        float* lds_h = smem;
        const int wv   = tid >> 6, lane = tid & 63;
        const int quad = lane >> 5, lid = lane & 31;

        const int nt = item >> 6, mc = item & 63;
        const int ny0 = (nt / 6) * 16, nx0 = (nt % 6) * 16;
        const int my0 = (mc & 7) * 12, mx0 = (mc >> 3) * 16;

        const int dx = (mx0 > nx0 + 15) ? mx0 - (nx0 + 15)
                     : ((nx0 > mx0 + 15) ? nx0 - (mx0 + 15) : 0);
        const int lim = TRUNC2 - dx * dx;            // >= 0 (host-culled)
        int T = (int)sqrtf((float)lim);
        T -= (T * T > lim);
        T += ((T + 1) * (T + 1) <= lim);

        int blo = ny0 - T - my0;      blo = blo < 0 ? 0 : blo;
        int bhi = ny0 + 15 + T - my0; bhi = bhi > 11 ? 11 : bhi;

        {   // stage featx rows blo..bhi: [seg][16 px][8 floats]
            float4* dst = (float4*)lds_h;
            for (int i = blo * 32 + tid; i < (bhi + 1) * 32; i += 256) {
                const int seg = i >> 5, off = i & 31;
                dst[i] = ((const float4*)(featx +
                          (size_t)((my0 + seg) * WW + mx0) * 8))[off];
            }
        }
        __syncthreads();

        const int by0 = ny0 + 4 * wv;
        int lo = by0 - T - my0;     lo = lo < 0 ? 0 : lo;
        int hi = by0 + 3 + T - my0; hi = hi > 11 ? 11 : hi;

        if (lo <= hi) {                              // wave-uniform
            const int row = lid >> 4, col = lid & 15;
            const int n0 = (by0 + row) * WW + nx0 + col;
            const int n1 = n0 + 2 * WW;
            const float4 g0a = *(const float4*)(featx + (size_t)n0 * 8);
            const float4 g0b = *(const float4*)(featx + (size_t)n0 * 8 + 4);
            const float4 g1a = *(const float4*)(featx + (size_t)n1 * 8);
            const float4 g1b = *(const float4*)(featx + (size_t)n1 * 8 + 4);

            f32x16 acc0, acc1;
            #pragma unroll
            for (int r = 0; r < 16; r++) { acc0[r] = 0.f; acc1[r] = 0.f; }

            int mg = (my0 + lo) * WW + mx0 + quad * 8;
            for (int step = lo; step <= hi; step++, mg += WW) {
                bf16x8 afrag = *(const bf16x8*)(pTcur + (size_t)lid * NN + mg);

                const float* h = lds_h + (step * 16 + quad * 8) * 8;
                float kb0[8], kb1[8];
                #pragma unroll
                for (int j = 0; j < 8; j++) {
                    float4 ha = *(const float4*)(h + j * 8);
                    float4 hb = *(const float4*)(h + j * 8 + 4);
                    float s0 = g0a.x + ha.x;
                    s0 = fmaf(g0a.y, ha.y, s0);
                    s0 = fmaf(g0a.z, ha.z, s0);
                    s0 = fmaf(g0a.w, ha.w, s0);
                    s0 = fmaf(g0b.x, hb.x, s0);
                    s0 = fmaf(g0b.y, hb.y, s0);
                    kb0[j] = fexp2(s0);
                    float s1 = g1a.x + ha.x;
                    s1 = fmaf(g1a.y, ha.y, s1);
                    s1 = fmaf(g1a.z, ha.z, s1);
                    s1 = fmaf(g1a.w, ha.w, s1);
                    s1 = fmaf(g1b.x, hb.x, s1);
                    s1 = fmaf(g1b.y, hb.y, s1);
                    kb1[j] = fexp2(s1);
                }
                bf16x8 b0, b1;
                #pragma unroll
                for (int j = 0; j < 8; j++) { b0[j] = f2b(kb0[j]); b1[j] = f2b(kb1[j]); }

                acc0 = __builtin_amdgcn_mfma_f32_32x32x16_bf16(afrag, b0, acc0, 0, 0, 0);
                acc1 = __builtin_amdgcn_mfma_f32_32x32x16_bf16(afrag, b1, acc1, 0, 0, 0);
            }

            #pragma unroll
            for (int r = 0; r < 16; r++) {
                int c = (r & 3) + 8 * (r >> 2) + 4 * quad;
                if (c < CC) {
                    atomicAdd(&bil[(size_t)c * NN + n0], acc0[r]);
                    atomicAdd(&bil[(size_t)c * NN + n1], acc1[r]);
                }
            }
        }

        __threadfence();                 // release our bil adds
        __syncthreads();
        if (tid == 0) {
            int old = atomicAdd(&cnt[nt], 1);
            if (old == c_TT.expct[nt] - 1) { fin[0] = 1; fin[1] = nt; }
        }
        __syncthreads();
    } else {
        // ---------------- spatial blur, one (channel, 12-row strip) per block
        float* A   = smem;           // up to 52 rows x 96
        float* B2  = smem + 4992;    // 12 x 96
        float* w_s = smem + 6144;    // 21 weights
        const int b2 = item - BLURKEY;
        const int c = b2 % CC;
        const int strip = b2 / CC;
        const int y0 = strip * SROWS;
        const int ylo = (y0 - RS < 0) ? 0 : y0 - RS;
        const int yhi = (y0 + SROWS - 1 + RS > HH - 1) ? HH - 1 : y0 + SROWS - 1 + RS;
        const int nrows = yhi - ylo + 1;

        if (tid <= RS) w_s[tid] = fexp2(-(float)(tid*tid) * (L2E / 18.f));
        const __hip_bfloat16* src = pTcur + (size_t)c * NN + ylo * WW;
        for (int i = tid; i < nrows * WW; i += 256)
            A[i] = __bfloat162float(src[i]);
        __syncthreads();

        for (int i = tid; i < SROWS * WW; i += 256) {
            const int yo = y0 + i / WW;
            const int x  = i % WW;
            float acc = A[(yo - ylo) * WW + x];
            #pragma unroll
            for (int d = 1; d <= RS; d++) {
                float s = 0.f;
                if (yo - d >= 0)  s += A[(yo - d - ylo) * WW + x];
                if (yo + d < HH)  s += A[(yo + d - ylo) * WW + x];
                acc = fmaf(w_s[d], s, acc);
            }
            B2[i] = acc;
        }
        __syncthreads();

        for (int i = tid; i < SROWS * WW; i += 256) {
            const int r = i / WW, x = i % WW;
            float acc = B2[i];
            #pragma unroll
            for (int d = 1; d <= RS; d++) {
                float s = 0.f;
                if (x - d >= 0)  s += B2[r * WW + x - d];
                if (x + d < WW)  s += B2[r * WW + x + d];
                acc = fmaf(w_s[d], s, acc);
            }
            s2T[(size_t)c * NN + (y0 + r) * WW + x] = acc;
        }

        __threadfence();                 // release our s2T stores
        __syncthreads();
        if (tid == 0) {
            int nf = 0;
            const int r0 = (12 * strip) / 16;
            int r1 = (12 * strip + 11) / 16; if (r1 > 5) r1 = 5;
            for (int r = r0; r <= r1; r++)
                for (int xt = 0; xt < 6; xt++) {
                    const int nt2 = r * 6 + xt;
                    int old = atomicAdd(&cnt[nt2], 1);
                    if (old == c_TT.expct[nt2] - 1) fin[1 + nf++] = nt2;
                }
            fin[0] = nf;
        }
        __syncthreads();
    }

    // ---------------- inline update for tiles this block completed
    const int nf = fin[0];
    if (nf == 0) return;
    __threadfence();                     // acquire other blocks' bil/s2T

    float* sc  = smem;                   // [441]
    float* sws = smem + 448;
    float* swb = smem + 480;
    for (int i = tid; i < CC*CC; i += 256) sc[i] = par[2*CC + i];
    if (tid < CC) { sws[tid] = par[tid]; swb[tid] = par[CC + tid]; }
    __syncthreads();

    const int is_f32 = last ? rdflag(flag32) : 0;

    for (int t = 0; t < nf; t++) {
        const int nt2 = fin[1 + t];
        const int n = ((nt2 / 6) * 16 + (tid >> 4)) * WW + (nt2 % 6) * 16 + (tid & 15);

        float msg[CC];
        #pragma unroll
        for (int c = 0; c < CC; c++) {
            msg[c] = fmaf(s2T[(size_t)c*NN + n], sws[c],
                          bil[(size_t)c*NN + n] * swb[c]);
            bil[(size_t)c*NN + n] = 0.f;
        }

        float qv[CC];
        float mx = -1e30f;
        #pragma unroll
        for (int c = 0; c < CC; c++) {
            float pw = 0.f;
            #pragma unroll
            for (int cp = 0; cp < CC; cp++) pw = fmaf(msg[cp], sc[c*CC + cp], pw);
            qv[c] = uf[(size_t)n*CC + c] - pw;
            mx = fmaxf(mx, qv[c]);
        }

        if (last) {
            #pragma unroll
            for (int c = 0; c < CC; c++) {
                if (is_f32) ((float*)out)[(size_t)n*CC + c] = qv[c];
                else ((__hip_bfloat16*)out)[(size_t)n*CC + c] = __float2bfloat16(qv[c]);
            }
        } else {
            float s = 0.f;
            #pragma unroll
            for (int c = 0; c < CC; c++) { qv[c] = fexp(qv[c] - mx); s += qv[c]; }
            float inv = 1.f / s;
            #pragma unroll
            for (int c = 0; c < CC; c++)
                pTnxt[(size_t)c*NN + n] = __float2bfloat16(qv[c] * inv);
        }
        if (tid == 0) cnt[nt2] = 0;      // reset for next launch (kernel-end release)
    }
}

extern "C" void kernel_launch(void* const* d_in, const int* in_sizes, int n_in,
                              void* d_out, int out_size, void* d_ws, size_t ws_size,
                              hipStream_t stream)
{
    float* ws = (float*)d_ws;
    int*   flag32 = (int*)ws;                    // [0..32)
    float* par    = ws + 32;                     // 483 used
    float* featx  = ws + 544;                    // NN*8 = 73728 floats
    __hip_bfloat16* pT0 = (__hip_bfloat16*)(ws + 74272);    // 147456 floats
    __hip_bfloat16* pT1 = (__hip_bfloat16*)(ws + 221728);   // 147456 floats
    float* uf  = ws + 369184;                    // NELEM
    float* s2T = uf + NELEM;                     // NELEM (c-major)
    float* bil = s2T + NELEM;                    // NELEM (c-major)
    int*   cnt = (int*)(bil + NELEM);            // 36 ints; total ~3.8 MB

    k_sniff<<<32, 256, 0, stream>>>((const unsigned short*)d_in[0], flag32);
    k_prep<<<NN/256, 256, 0, stream>>>(d_in[0], d_in[1], d_in[2], d_in[3], d_in[4],
                                       flag32, uf, featx, par, bil, pT0, cnt);

    for (int it = 0; it < 5; it++) {
        __hip_bfloat16* cur = (it & 1) ? pT1 : pT0;
        __hip_bfloat16* nxt = (it & 1) ? pT0 : pT1;
        k_work<<<TT.n, 256, 0, stream>>>(cur, nxt, featx, bil, s2T, uf, par,
                                         flag32, cnt, d_out, (it == 4) ? 1 : 0);
    }
}

// Round 13
// 235.627 us; speedup vs baseline: 2.7410x; 2.7410x over previous
//
#include <hip/hip_runtime.h>
#include <hip/hip_bf16.h>

#define HH 96
#define WW 96
#define CC 21
#define NN (HH*WW)          // 9216
#define NELEM (NN*CC)       // 193536
#define RS 20
#define NPAR (2*CC + CC*CC)
#define L2E 1.4426950408889634f
#define NMC 48              // 12x16 m-chunks: 8 y * 6 x
#define NBB (36*NMC)
#define NBLUR (CC*8)        // 168 blur items
#define SROWS 12
#define TRUNC2 900          // 30^2 (validated R10: absmax 0.015625 unchanged)
#define BLURKEY 0x10000

typedef short bf16x8 __attribute__((ext_vector_type(8)));
typedef float f32x16 __attribute__((ext_vector_type(16)));
typedef int   i32x4  __attribute__((ext_vector_type(4)));

__device__ __forceinline__ float fexp2(float x) { return __builtin_amdgcn_exp2f(x); }
__device__ __forceinline__ float fexp(float x)  { return __builtin_amdgcn_exp2f(x * L2E); }

__device__ __forceinline__ short f2b(float f) {
    __hip_bfloat16 h = __float2bfloat16(f);
    short s; __builtin_memcpy(&s, &h, 2); return s;
}
__device__ __forceinline__ float b2f(short s) {
    __hip_bfloat16 h; __builtin_memcpy(&h, &s, 2);
    return __bfloat162float(h);
}

// ---- compile-time work table (unchanged from R10)
struct Tab { int n; int k[NBB + NBLUR]; };
constexpr Tab build_tab() {
    Tab t{};
    int key[NBB + NBLUR] = {};
    int cst[NBB + NBLUR] = {};
    int m = 0;
    for (int nt = 0; nt < 36; nt++)
        for (int mc = 0; mc < NMC; mc++) {
            const int ny0 = (nt / 6) * 16, nx0 = (nt % 6) * 16;
            const int my0 = (mc & 7) * 12, mx0 = (mc >> 3) * 16;
            const int dx = (mx0 > nx0 + 15) ? mx0 - (nx0 + 15)
                         : ((nx0 > mx0 + 15) ? nx0 - (mx0 + 15) : 0);
            const int lim = TRUNC2 - dx * dx;
            if (lim < 0) continue;
            int T = 0;
            while ((T + 1) * (T + 1) <= lim) T++;
            int cost = 0;
            for (int wv = 0; wv < 4; wv++) {
                const int by0 = ny0 + 4 * wv;
                int lo = by0 - T - my0;     if (lo < 0)  lo = 0;
                int hi = by0 + 3 + T - my0; if (hi > 11) hi = 11;
                if (lo <= hi) cost += hi - lo + 1;
            }
            if (cost == 0) continue;
            key[m] = (nt << 6) | mc; cst[m] = cost; m++;
        }
    for (int b = 0; b < NBLUR; b++) { key[m] = BLURKEY + b; cst[m] = 20; m++; }
    for (int c = 48; c >= 1; c--)                 // stable counting sort, desc
        for (int i = 0; i < m; i++)
            if (cst[i] == c) t.k[t.n++] = key[i];
    return t;
}
constexpr Tab TT = build_tab();
__device__ __constant__ Tab c_TT = TT;

// ---- dtype sniff: bf16 data never contains exp=0xFF bit patterns.
__global__ void k_sniff(const unsigned short* __restrict__ u16, int* __restrict__ flag32) {
    __shared__ int sfound;
    if (threadIdx.x == 0) sfound = 0;
    __syncthreads();
    const int base = blockIdx.x * (NELEM/32);
    int found = 0;
    for (int i = base + threadIdx.x; i < base + NELEM/32; i += 256) {
        unsigned v = u16[i];
        if ((v & 0x7F80u) == 0x7F80u) found = 1;
    }
    if (found) sfound = 1;
    __syncthreads();
    if (threadIdx.x == 0) flag32[blockIdx.x] = sfound;
}

__device__ __forceinline__ int rdflag(const int* __restrict__ flag32) {
    int f = 0;
    #pragma unroll
    for (int i = 0; i < 32; i++) f |= flag32[i];
    return f;
}

// Fused prep (unchanged from R10)
__global__ __launch_bounds__(256) void k_prep(
    const void* __restrict__ u, const void* __restrict__ img,
    const void* __restrict__ wS, const void* __restrict__ wB,
    const void* __restrict__ compat, const int* __restrict__ flag32,
    float* __restrict__ uf, float* __restrict__ featx, float* __restrict__ par,
    float* __restrict__ bil, __hip_bfloat16* __restrict__ pT)
{
    const int f = rdflag(flag32);
    const int tid = threadIdx.x;
    const int n = blockIdx.x * 256 + tid;

    if (blockIdx.x == 0) {
        for (int i = tid; i < NPAR; i += 256) {
            const void* src; int j;
            if (i < CC)        { src = wS;     j = i; }
            else if (i < 2*CC) { src = wB;     j = i - CC; }
            else               { src = compat; j = i - 2*CC; }
            par[i] = f ? ((const float*)src)[j]
                       : __bfloat162float(((const __hip_bfloat16*)src)[j]);
        }
    }

    {
        float c0, c1, c2;
        if (f) { const float* p = (const float*)img;
                 c0 = p[3*n]; c1 = p[3*n+1]; c2 = p[3*n+2]; }
        else   { const __hip_bfloat16* p = (const __hip_bfloat16*)img;
                 c0 = __bfloat162float(p[3*n]); c1 = __bfloat162float(p[3*n+1]);
                 c2 = __bfloat162float(p[3*n+2]); }
        float ym = (float)(n / WW), xm = (float)(n % WW);
        const float sc = 0.15014029f;   // sqrt(2*L2E/128)
        const float cf = 9.6089787f;    // sqrt(64*L2E)
        featx[8*n + 0] = -L2E * (fmaf(ym, ym, xm*xm) * 0.0078125f
                                 + 32.f * (c0*c0 + c1*c1 + c2*c2));
        featx[8*n + 1] = sc * ym;
        featx[8*n + 2] = sc * xm;
        featx[8*n + 3] = cf * c0;
        featx[8*n + 4] = cf * c1;
        featx[8*n + 5] = cf * c2;
        featx[8*n + 6] = 0.f;
        featx[8*n + 7] = 0.f;
    }

    float v[CC];
    float mx = -1e30f;
    #pragma unroll
    for (int c = 0; c < CC; c++) {
        float uv = f ? ((const float*)u)[n*CC + c]
                     : __bfloat162float(((const __hip_bfloat16*)u)[n*CC + c]);
        uf[n*CC + c] = uv;
        v[c] = uv;
        mx = fmaxf(mx, uv);
    }
    float s = 0.f;
    #pragma unroll
    for (int c = 0; c < CC; c++) { v[c] = fexp(v[c] - mx); s += v[c]; }
    float inv = 1.f / s;
    #pragma unroll
    for (int c = 0; c < CC; c++) {
        pT[(size_t)c*NN + n] = __float2bfloat16(v[c] * inv);
        bil[(size_t)c*NN + n] = 0.f;
    }
}

// Work kernel: bilateral kernel-evaluation now runs on the MATRIX CORES.
// S[m][n] = sum_d H[m][d]*G[n][d] (7 dims) via two 32x32x16 MFMAs with
// hi/lo-split bf16 features: A=[Hhi|Hlo], B1=[Ghi|Ghi], B2=[Glo|Glo]
// => S = (Hhi+Hlo)(Ghi+Glo), split-exact. Then exp2, pack to bf16,
// quad-swap (shfl_xor 32) from D-layout to B-fragment layout, and the
// usual bil MFMA. Per 32 m-px: ~130 instrs vs ~340 in the FMA version.
__global__ __launch_bounds__(256) void k_work(
    const __hip_bfloat16* __restrict__ pT,   // [32][NN] bf16 (rows 21..31 garbage)
    const float* __restrict__ featx,         // [NN][8]
    float* __restrict__ bil,                 // [CC][NN] atomic accum
    float* __restrict__ s2T)                 // [CC][NN] spatial out
{
    __shared__ float smem[6176];             // bilateral: 6KB hs; blur: 4992+1152+32
    const int tid = threadIdx.x;
    const int item = c_TT.k[blockIdx.x];

    if (item < BLURKEY) {
        short* hs = (short*)smem;            // [6 grp][hi/lo 256][32 px * 8]
        const int wv   = tid >> 6, lane = tid & 63;
        const int quad = lane >> 5, lid = lane & 31;

        const int nt = item >> 6, mc = item & 63;
        const int ny0 = (nt / 6) * 16, nx0 = (nt % 6) * 16;
        const int my0 = (mc & 7) * 12, mx0 = (mc >> 3) * 16;

        const int dx = (mx0 > nx0 + 15) ? mx0 - (nx0 + 15)
                     : ((nx0 > mx0 + 15) ? nx0 - (mx0 + 15) : 0);
        const int lim = TRUNC2 - dx * dx;            // >= 0 (host-culled)
        int T = (int)sqrtf((float)lim);
        T -= (T * T > lim);
        T += ((T + 1) * (T + 1) <= lim);

        // stage split-H for all 12 chunk rows: grp g = rows 2g,2g+1 (32 px)
        for (int i = tid; i < 192; i += 256) {
            const int mrow = i >> 4, mcol = i & 15;
            const float* f = featx + (size_t)((my0 + mrow) * WW + mx0 + mcol) * 8;
            const int grp = mrow >> 1;
            const int li  = ((mrow & 1) << 4) | mcol;
            short* dhi = hs + grp * 512 + li * 8;
            float hv[8] = {1.f, f[0], f[1], f[2], f[3], f[4], f[5], 0.f};
            #pragma unroll
            for (int j = 0; j < 8; j++) {
                short hb = f2b(hv[j]);
                dhi[j] = hb;
                dhi[256 + j] = f2b(hv[j] - b2f(hb));
            }
        }
        __syncthreads();

        const int by0 = ny0 + 4 * wv;
        int lo = by0 - T - my0;     lo = lo < 0 ? 0 : lo;
        int hi = by0 + 3 + T - my0; hi = hi > 11 ? 11 : hi;
        if (lo > hi) return;   // wave-uniform; no barriers below

        const int row = lid >> 4, col = lid & 15;
        const int n0 = (by0 + row) * WW + nx0 + col;     // acc0 pixel
        const int n1 = n0 + 2 * WW;                      // acc1 pixel

        // split-G fragments (quad-uniform B operands), registers for the chunk
        bf16x8 gh0, gl0, gh1, gl1;
        {
            const float* f0 = featx + (size_t)n0 * 8;
            const float* f1 = featx + (size_t)n1 * 8;
            float g0v[8] = {f0[0], 1.f, f0[1], f0[2], f0[3], f0[4], f0[5], 0.f};
            float g1v[8] = {f1[0], 1.f, f1[1], f1[2], f1[3], f1[4], f1[5], 0.f};
            #pragma unroll
            for (int j = 0; j < 8; j++) {
                short h0b = f2b(g0v[j]); gh0[j] = h0b;
                gl0[j] = f2b(g0v[j] - b2f(h0b));
                short h1b = f2b(g1v[j]); gh1[j] = h1b;
                gl1[j] = f2b(g1v[j] - b2f(h1b));
            }
        }

        f32x16 acc0, acc1, zz;
        #pragma unroll
        for (int r = 0; r < 16; r++) { acc0[r] = 0.f; acc1[r] = 0.f; zz[r] = 0.f; }

        const int glo2 = lo >> 1, ghi2 = hi >> 1;   // widen to full 2-row groups
        for (int g = glo2; g <= ghi2; g++) {
            bf16x8 A1 = *(const bf16x8*)(hs + g * 512 + quad * 256 + lid * 8);
            const int mrow = my0 + 2 * g;
            const __hip_bfloat16* pbase = pT + (size_t)lid * NN + mrow * WW + mx0 + quad * 8;
            bf16x8 afA = *(const bf16x8*)(pbase);
            bf16x8 afB = *(const bf16x8*)(pbase + WW);

            // ---------- n-set 0
            {
                f32x16 V = __builtin_amdgcn_mfma_f32_32x32x16_bf16(A1, gh0, zz, 0, 0, 0);
                V = __builtin_amdgcn_mfma_f32_32x32x16_bf16(A1, gl0, V, 0, 0, 0);
                #pragma unroll
                for (int r = 0; r < 16; r++) V[r] = fexp2(V[r]);
                int P[8];
                #pragma unroll
                for (int t2 = 0; t2 < 8; t2++)
                    P[t2] = (int)(((unsigned)(unsigned short)f2b(V[2*t2]))
                          | (((unsigned)(unsigned short)f2b(V[2*t2+1])) << 16));
                int S0 = __shfl_xor(P[0], 32), S1 = __shfl_xor(P[1], 32);
                int S2 = __shfl_xor(P[2], 32), S3 = __shfl_xor(P[3], 32);
                int S4 = __shfl_xor(P[4], 32), S5 = __shfl_xor(P[5], 32);
                int S6 = __shfl_xor(P[6], 32), S7 = __shfl_xor(P[7], 32);
                // D-layout m-pairs -> B-frag k-order (k = m 0..15 row 2g; 16..31 row 2g+1)
                i32x4 b1i = { quad ? S2 : P[0], quad ? S3 : P[1],
                              quad ? P[2] : S0, quad ? P[3] : S1 };
                i32x4 b2i = { quad ? S6 : P[4], quad ? S7 : P[5],
                              quad ? P[6] : S4, quad ? P[7] : S5 };
                bf16x8 b1, b2;
                __builtin_memcpy(&b1, &b1i, 16);
                __builtin_memcpy(&b2, &b2i, 16);
                acc0 = __builtin_amdgcn_mfma_f32_32x32x16_bf16(afA, b1, acc0, 0, 0, 0);
                acc0 = __builtin_amdgcn_mfma_f32_32x32x16_bf16(afB, b2, acc0, 0, 0, 0);
            }
            // ---------- n-set 1
            {
                f32x16 V = __builtin_amdgcn_mfma_f32_32x32x16_bf16(A1, gh1, zz, 0, 0, 0);
                V = __builtin_amdgcn_mfma_f32_32x32x16_bf16(A1, gl1, V, 0, 0, 0);
                #pragma unroll
                for (int r = 0; r < 16; r++) V[r] = fexp2(V[r]);
                int P[8];
                #pragma unroll
                for (int t2 = 0; t2 < 8; t2++)
                    P[t2] = (int)(((unsigned)(unsigned short)f2b(V[2*t2]))
                          | (((unsigned)(unsigned short)f2b(V[2*t2+1])) << 16));
                int S0 = __shfl_xor(P[0], 32), S1 = __shfl_xor(P[1], 32);
                int S2 = __shfl_xor(P[2], 32), S3 = __shfl_xor(P[3], 32);
                int S4 = __shfl_xor(P[4], 32), S5 = __shfl_xor(P[5], 32);
                int S6 = __shfl_xor(P[6], 32), S7 = __shfl_xor(P[7], 32);
                i32x4 b1i = { quad ? S2 : P[0], quad ? S3 : P[1],
                              quad ? P[2] : S0, quad ? P[3] : S1 };
                i32x4 b2i = { quad ? S6 : P[4], quad ? S7 : P[5],
                              quad ? P[6] : S4, quad ? P[7] : S5 };
                bf16x8 b1, b2;
                __builtin_memcpy(&b1, &b1i, 16);
                __builtin_memcpy(&b2, &b2i, 16);
                acc1 = __builtin_amdgcn_mfma_f32_32x32x16_bf16(afA, b1, acc1, 0, 0, 0);
                acc1 = __builtin_amdgcn_mfma_f32_32x32x16_bf16(afB, b2, acc1, 0, 0, 0);
            }
        }

        // D layout: col(n) = lid, row(c) = (r&3) + 8*(r>>2) + 4*quad
        #pragma unroll
        for (int r = 0; r < 16; r++) {
            int c = (r & 3) + 8 * (r >> 2) + 4 * quad;
            if (c < CC) {
                atomicAdd(&bil[(size_t)c * NN + n0], acc0[r]);
                atomicAdd(&bil[(size_t)c * NN + n1], acc1[r]);
            }
        }
    } else {
        // ---------------- spatial blur, one (channel, 12-row strip) per block
        float* A   = smem;           // up to 52 rows x 96
        float* B2  = smem + 4992;    // 12 x 96
        float* w_s = smem + 6144;    // 21 weights
        const int b2 = item - BLURKEY;
        const int c = b2 % CC;
        const int strip = b2 / CC;
        const int y0 = strip * SROWS;
        const int ylo = (y0 - RS < 0) ? 0 : y0 - RS;
        const int yhi = (y0 + SROWS - 1 + RS > HH - 1) ? HH - 1 : y0 + SROWS - 1 + RS;
        const int nrows = yhi - ylo + 1;

        if (tid <= RS) w_s[tid] = fexp2(-(float)(tid*tid) * (L2E / 18.f));
        const __hip_bfloat16* src = pT + (size_t)c * NN + ylo * WW;
        for (int i = tid; i < nrows * WW; i += 256)
            A[i] = __bfloat162float(src[i]);
        __syncthreads();

        for (int i = tid; i < SROWS * WW; i += 256) {
            const int yo = y0 + i / WW;
            const int x  = i % WW;
            float acc = A[(yo - ylo) * WW + x];
            #pragma unroll
            for (int d = 1; d <= RS; d++) {
                float s = 0.f;
                if (yo - d >= 0)  s += A[(yo - d - ylo) * WW + x];
                if (yo + d < HH)  s += A[(yo + d - ylo) * WW + x];
                acc = fmaf(w_s[d], s, acc);
            }
            B2[i] = acc;
        }
        __syncthreads();

        for (int i = tid; i < SROWS * WW; i += 256) {
            const int r = i / WW, x = i % WW;
            float acc = B2[i];
            #pragma unroll
            for (int d = 1; d <= RS; d++) {
                float s = 0.f;
                if (x - d >= 0)  s += B2[r * WW + x - d];
                if (x + d < WW)  s += B2[r * WW + x + d];
                acc = fmaf(w_s[d], s, acc);
            }
            s2T[(size_t)c * NN + (y0 + r) * WW + x] = acc;
        }
    }
}

// Combine spatial+bilateral, compatibility, q-update, fused softmax -> pT.
// (unchanged from R10)
__global__ __launch_bounds__(256) void k_update(
    float* __restrict__ bil, const float* __restrict__ s2T,
    const float* __restrict__ uf, const float* __restrict__ par,
    const int* __restrict__ flag32,
    __hip_bfloat16* __restrict__ pT, void* __restrict__ out, int last)
{
    __shared__ float sc[CC*CC + 1];
    __shared__ float sws[CC], swb[CC];
    const int tid = threadIdx.x;
    for (int i = tid; i < CC*CC; i += 256) sc[i] = par[2*CC + i];
    if (tid == 0) sc[CC*CC] = 0.f;
    if (tid < CC) { sws[tid] = par[tid]; swb[tid] = par[CC + tid]; }
    __syncthreads();

    const int half = tid & 1;
    const int n = blockIdx.x * 128 + (tid >> 1);

    float msg[11];
    #pragma unroll
    for (int k = 0; k < 11; k++) {
        const int cp = 2*k + half;
        if (cp < CC) {
            msg[k] = fmaf(s2T[(size_t)cp*NN + n], sws[cp],
                          bil[(size_t)cp*NN + n] * swb[cp]);
            bil[(size_t)cp*NN + n] = 0.f;
        } else msg[k] = 0.f;
    }

    float pw[CC];
    #pragma unroll
    for (int c = 0; c < CC; c++) {
        float a = msg[0] * sc[c*CC + half];
        #pragma unroll
        for (int k = 1; k < 11; k++)
            a = fmaf(msg[k], sc[c*CC + 2*k + half], a);
        pw[c] = a;
    }
    #pragma unroll
    for (int c = 0; c < CC; c++)
        pw[c] += __shfl_xor(pw[c], 1, 64);

    float qv[CC];
    float mx = -1e30f;
    #pragma unroll
    for (int c = 0; c < CC; c++) {
        qv[c] = uf[(size_t)n*CC + c] - pw[c];
        mx = fmaxf(mx, qv[c]);
    }

    if (last) {
        const int is_f32 = rdflag(flag32);
        #pragma unroll
        for (int k = 0; k < 11; k++) {
            const int ce = 2*k, co = (k < 10) ? 2*k + 1 : 0;
            float v = half ? qv[co] : qv[ce];
            const int c = 2*k + half;
            if (c < CC) {
                if (is_f32) ((float*)out)[(size_t)n*CC + c] = v;
                else ((__hip_bfloat16*)out)[(size_t)n*CC + c] = __float2bfloat16(v);
            }
        }
    } else {
        float ex[11]; float ssum = 0.f;
        #pragma unroll
        for (int k = 0; k < 11; k++) {
            const int ce = 2*k, co = (k < 10) ? 2*k + 1 : 0;
            float v = half ? qv[co] : qv[ce];
            float e = fexp(v - mx);
            if (2*k + half < CC) ssum += e;
            ex[k] = e;
        }
        ssum += __shfl_xor(ssum, 1, 64);
        const float inv = 1.f / ssum;
        #pragma unroll
        for (int k = 0; k < 11; k++) {
            const int c = 2*k + half;
            if (c < CC) pT[(size_t)c*NN + n] = __float2bfloat16(ex[k] * inv);
        }
    }
}

extern "C" void kernel_launch(void* const* d_in, const int* in_sizes, int n_in,
                              void* d_out, int out_size, void* d_ws, size_t ws_size,
                              hipStream_t stream)
{
    float* ws = (float*)d_ws;
    int*   flag32 = (int*)ws;                    // [0..32)
    float* par    = ws + 32;                     // 483 used
    float* featx  = ws + 544;                    // NN*8 = 73728 floats
    __hip_bfloat16* pT = (__hip_bfloat16*)(ws + 74272);   // 32*NN bf16 = 147456 floats
    float* uf  = ws + 221728;                    // NELEM
    float* s2T = uf + NELEM;                     // NELEM (c-major)
    float* bil = s2T + NELEM;                    // NELEM (c-major); total ~3.2 MB

    k_sniff<<<32, 256, 0, stream>>>((const unsigned short*)d_in[0], flag32);
    k_prep<<<NN/256, 256, 0, stream>>>(d_in[0], d_in[1], d_in[2], d_in[3], d_in[4],
                                       flag32, uf, featx, par, bil, pT);

    for (int it = 0; it < 5; it++) {
        k_work<<<TT.n, 256, 0, stream>>>(pT, featx, bil, s2T);
        k_update<<<NN/128, 256, 0, stream>>>(bil, s2T, uf, par, flag32,
                                             pT, d_out, (it == 4) ? 1 : 0);
    }
}